// Round 15
// baseline (173.413 us; speedup 1.0000x reference)
//
#include <hip/hip_runtime.h>

// NavierStokesLoss: fused jet-propagation (8 channels/point) through
// 4->256->256->5 tanh MLP. R15 = R13 (112.5us, validated) + T14 issue-early
// B prefetch: GEMM2's 16 L2-resident B-loads move into a 4-deep register
// ring; the first 8 issue BEFORE layer-1 (latency hides under L1 VALU +
// barrier), the loop refills 4 ahead. sched_barrier(0) pins the prefetch.
// Single-base +-2048-bias B addressing (R14-validated) keeps regs at 84<=85.
// fp8 MFMA (absmax 0.002, R9-R13); 4-bit XOR swizzle (0 conflicts, R12/R13);
// in-register G3 tail (R11-R13); launch_bounds(512,6) -> 3 blocks/CU.

#define NPTS 65536
#define BP   8
#define NBLK (NPTS / BP)      // 8192
#define W3T_OFF 135168
#define PART_OFF 143360

typedef float f32x4 __attribute__((ext_vector_type(4)));

static __device__ __forceinline__ unsigned cvtpk_fp8(float lo, float hi){
  unsigned r = 0;
  asm("v_cvt_pk_fp8_f32 %0, %1, %2" : "+v"(r) : "v"(lo), "v"(hi));
  return r;   // bytes [0]=fp8(lo), [1]=fp8(hi)
}
static __device__ __forceinline__ float fast_tanh(float x){
  float e = __builtin_amdgcn_exp2f(x * 2.8853900817779268f);   // exp(2x)
  return 1.f - 2.f * __builtin_amdgcn_rcpf(e + 1.f);
}

// W2 (256x256 f32, [k][j]) -> w2t fp8 [j][256] (transposed, unpadded)
__global__ void prep_w2t(const float* __restrict__ W2, unsigned char* __restrict__ w2t){
  int kp = blockIdx.x, j = threadIdx.x;          // 128 k-pairs
  float lo = W2[(2*kp    )*256 + j];
  float hi = W2[(2*kp + 1)*256 + j];
  *(unsigned short*)(w2t + j*256 + 2*kp) = (unsigned short)cvtpk_fp8(lo, hi);
}
// W3 (256x5 f32, [k][n]) -> w3t fp8 [16][256] (transposed, rows 5..15 zero)
__global__ void prep_w3t(const float* __restrict__ W3, unsigned char* __restrict__ w3t){
  int n = blockIdx.x, k2 = threadIdx.x * 2;      // 16 x 128
  float lo = (n < 5) ? W3[k2*5 + n]       : 0.f;
  float hi = (n < 5) ? W3[(k2+1)*5 + n]   : 0.f;
  *(unsigned short*)(w3t + n*256 + k2) = (unsigned short)cvtpk_fp8(lo, hi);
}

// Jet-tile row layout (64 rows x 256 fp8, 256B rows, XOR swizzle (row&15)<<3):
//   row(p,c) = (p&4)*8 + (c&4)*4 + (p&3)*4 + (c&3)
__launch_bounds__(512, 6)
__global__ void ns_main(const float* __restrict__ pts, const float* __restrict__ times,
                        const float* __restrict__ visc,
                        const float* __restrict__ W1, const float* __restrict__ b1,
                        const float* __restrict__ b2, const float* __restrict__ b3,
                        const unsigned char* __restrict__ w2t,
                        const unsigned char* __restrict__ w3t,
                        float* __restrict__ parts){
  __shared__ __align__(16) unsigned char sA[64 * 256];   // 16 KiB
  __shared__ float red[4];

  const int t   = threadIdx.x;
  const int blk = blockIdx.x;
  const int wid = t >> 6, lane = t & 63;
  const int g = lane >> 4, r16 = lane & 15;
  const int rsw = r16 << 3;   // (row&15)<<3 for rows {r16, 16+r16, 32+r16, 48+r16}

  // ---- T14: issue GEMM2 B-loads (ks 0..3) BEFORE layer-1 ----
  // single base, biased +2048: row (wid*32+r16) at k0-2048, row +16 at k0+2048
  const unsigned char* bp = w2t + (wid*32 + r16)*256 + g*8 + 2048;
  long breg[8];   // ring of 4 k-steps x 2 halves
  #pragma unroll
  for (int ks = 0; ks < 4; ++ks){
    breg[2*ks]   = *(const long*)(bp + (ks*32 - 2048));
    breg[2*ks+1] = *(const long*)(bp + (ks*32 + 2048));
  }
  __builtin_amdgcn_sched_barrier(0);   // pin prefetch ahead of L1

  // ---------------- layer 1: seed the jet, write fp8 A-tile ----------------
  {
    int p  = wid;               // 8 points, one wave each
    int jo = lane << 2;         // 4 consecutive j per thread
    int n  = blk * BP + p;
    float z0 = pts[n*3+0], z1 = pts[n*3+1], z2 = pts[n*3+2], z3 = times[n];
    float4 wa  = *(const float4*)(W1 + jo);
    float4 wb  = *(const float4*)(W1 + 256 + jo);
    float4 wcv = *(const float4*)(W1 + 512 + jo);
    float4 wd  = *(const float4*)(W1 + 768 + jo);
    float4 bb  = *(const float4*)(b1 + jo);
    float th[4], sg[4], m2[4];
    #pragma unroll
    for (int jj = 0; jj < 4; ++jj){
      float a = (&bb.x)[jj] + z0*(&wa.x)[jj] + z1*(&wb.x)[jj]
                            + z2*(&wcv.x)[jj] + z3*(&wd.x)[jj];
      float h = fast_tanh(a);
      th[jj] = h; sg[jj] = 1.f - h*h; m2[jj] = -2.f*h*sg[jj];
    }
    #pragma unroll
    for (int c = 0; c < 8; ++c){
      float x[4];
      #pragma unroll
      for (int jj = 0; jj < 4; ++jj){
        float w0 = (&wa.x)[jj], w1 = (&wb.x)[jj], w2 = (&wcv.x)[jj];
        float v;
        if      (c == 0) v = th[jj];
        else if (c == 1) v = sg[jj]*w0;
        else if (c == 2) v = sg[jj]*w1;
        else if (c == 3) v = sg[jj]*w2;
        else if (c == 4) v = sg[jj]*(&wd.x)[jj];
        else if (c == 5) v = m2[jj]*w0*w0;
        else if (c == 6) v = m2[jj]*w1*w1;
        else             v = m2[jj]*w2*w2;
        x[jj] = v;
      }
      int row = ((p & 4) << 3) + ((c & 4) << 2) + ((p & 3) << 2) + (c & 3);
      int off = row*256 + (jo ^ ((row & 15) << 3));
      unsigned v32 = cvtpk_fp8(x[0], x[1]) | (cvtpk_fp8(x[2], x[3]) << 16);
      *(unsigned*)(sA + off) = v32;
    }
  }
  __syncthreads();

  // ---------------- GEMM2: A(64x256) @ W2 cols wid*32..+31, fp8 MFMA ----------------
  f32x4 acc[4][2];
  #pragma unroll
  for (int a = 0; a < 4; ++a)
    #pragma unroll
    for (int b = 0; b < 2; ++b)
      acc[a][b] = (f32x4){0.f, 0.f, 0.f, 0.f};

  {
    int abase = r16*256;
    #pragma unroll
    for (int ks = 0; ks < 8; ++ks){
      int k0 = ks * 32;
      int X  = (k0 + (g << 3)) ^ rsw;
      long af0 = *(const long*)(sA + abase + X);
      long af1 = *(const long*)(sA + abase +  4096 + X);
      long af2 = *(const long*)(sA + abase +  8192 + X);
      long af3 = *(const long*)(sA + abase + 12288 + X);
      long b0  = breg[(ks & 3)*2];
      long b1f = breg[(ks & 3)*2 + 1];
      if (ks < 4){   // refill ring slot for ks+4
        breg[(ks & 3)*2]     = *(const long*)(bp + ((ks+4)*32 - 2048));
        breg[(ks & 3)*2 + 1] = *(const long*)(bp + ((ks+4)*32 + 2048));
      }
      __builtin_amdgcn_s_setprio(1);
      acc[0][0] = __builtin_amdgcn_mfma_f32_16x16x32_fp8_fp8(af0, b0,  acc[0][0], 0, 0, 0);
      acc[1][0] = __builtin_amdgcn_mfma_f32_16x16x32_fp8_fp8(af1, b0,  acc[1][0], 0, 0, 0);
      acc[2][0] = __builtin_amdgcn_mfma_f32_16x16x32_fp8_fp8(af2, b0,  acc[2][0], 0, 0, 0);
      acc[3][0] = __builtin_amdgcn_mfma_f32_16x16x32_fp8_fp8(af3, b0,  acc[3][0], 0, 0, 0);
      acc[0][1] = __builtin_amdgcn_mfma_f32_16x16x32_fp8_fp8(af0, b1f, acc[0][1], 0, 0, 0);
      acc[1][1] = __builtin_amdgcn_mfma_f32_16x16x32_fp8_fp8(af1, b1f, acc[1][1], 0, 0, 0);
      acc[2][1] = __builtin_amdgcn_mfma_f32_16x16x32_fp8_fp8(af2, b1f, acc[2][1], 0, 0, 0);
      acc[3][1] = __builtin_amdgcn_mfma_f32_16x16x32_fp8_fp8(af3, b1f, acc[3][1], 0, 0, 0);
      __builtin_amdgcn_s_setprio(0);
    }
  }
  __syncthreads();   // all A-tile reads complete before in-place overwrite

  // ------- recombine (tanh jet through layer-2), register-local, fp8 writes -------
  // (acc[0],acc[1]) = pts 0-3 ch-lo/hi of point g; (acc[2],acc[3]) = pts 4-7.
  {
    float b2c0 = b2[wid*32 + r16];
    float b2c1 = b2[wid*32 + 16 + r16];
    int wadr[2][4];   // [nt][c3]: byte addr for pr=0, ch-lo; +8192 pr=1; +4096 ch-hi
    #pragma unroll
    for (int nt = 0; nt < 2; ++nt){
      int colb = wid*32 + nt*16 + r16;
      #pragma unroll
      for (int c3 = 0; c3 < 4; ++c3)
        wadr[nt][c3] = (g*4 + c3)*256 + (colb ^ ((g*4 + c3) << 3));
    }
    #pragma unroll
    for (int pr = 0; pr < 2; ++pr){
      #pragma unroll
      for (int nt = 0; nt < 2; ++nt){
        f32x4 v = acc[2*pr][nt];     // value, dx, dy, dz
        f32x4 w = acc[2*pr+1][nt];   // dt, dxx, dyy, dzz
        float gv = fast_tanh(v[0] + (nt ? b2c1 : b2c0));
        float s2 = 1.f - gv*gv;
        float t2 = -2.f * gv * s2;
        float r0 = gv,      r1 = s2*v[1], r2 = s2*v[2], r3 = s2*v[3];
        float r4 = s2*w[0];
        float r5 = fmaf(t2*v[1], v[1], s2*w[1]);
        float r6 = fmaf(t2*v[2], v[2], s2*w[2]);
        float r7 = fmaf(t2*v[3], v[3], s2*w[3]);
        unsigned u;
        u = cvtpk_fp8(r0, r4);
        *(unsigned char*)(sA + wadr[nt][0] + pr*8192)        = (unsigned char)u;
        *(unsigned char*)(sA + wadr[nt][0] + pr*8192 + 4096) = (unsigned char)(u >> 8);
        u = cvtpk_fp8(r1, r5);
        *(unsigned char*)(sA + wadr[nt][1] + pr*8192)        = (unsigned char)u;
        *(unsigned char*)(sA + wadr[nt][1] + pr*8192 + 4096) = (unsigned char)(u >> 8);
        u = cvtpk_fp8(r2, r6);
        *(unsigned char*)(sA + wadr[nt][2] + pr*8192)        = (unsigned char)u;
        *(unsigned char*)(sA + wadr[nt][2] + pr*8192 + 4096) = (unsigned char)(u >> 8);
        u = cvtpk_fp8(r3, r7);
        *(unsigned char*)(sA + wadr[nt][3] + pr*8192)        = (unsigned char)u;
        *(unsigned char*)(sA + wadr[nt][3] + pr*8192 + 4096) = (unsigned char)(u >> 8);
      }
    }
  }
  __syncthreads();

  // ---- GEMM3 + in-register residual tail: waves 0-1, 4 points each ----
  // wave w: A rows w*32 + r16 (ch-lo) and +16 (ch-hi). Lane (g,r16):
  // point w*4+g, output index n = r16; a3a[q] = o[ch q][n], a3b[q] = o[ch 4+q][n].
  if (wid < 2){
    const unsigned char* w3p = w3t + r16*256 + g*8;
    int gbase = wid*8192 + r16*256;
    f32x4 a3a = (f32x4){0.f, 0.f, 0.f, 0.f};
    f32x4 a3b = (f32x4){0.f, 0.f, 0.f, 0.f};
    #pragma unroll
    for (int ks = 0; ks < 8; ++ks){
      int k0 = ks * 32;
      int X  = (k0 + (g << 3)) ^ rsw;
      long ava = *(const long*)(sA + gbase + X);
      long avb = *(const long*)(sA + gbase + 4096 + X);
      long bv3 = *(const long*)(w3p + k0);
      a3a = __builtin_amdgcn_mfma_f32_16x16x32_fp8_fp8(ava, bv3, a3a, 0, 0, 0);
      a3b = __builtin_amdgcn_mfma_f32_16x16x32_fp8_fp8(avb, bv3, a3b, 0, 0, 0);
    }
    float b3v = (r16 < 5) ? b3[r16] : 0.f;
    float o0 = a3a[0] + b3v;                   // value channel + bias
    float o1 = a3a[1], o2 = a3a[2], o3 = a3a[3];
    int sl = lane & 48;
    float u0   = __shfl(o0, sl | 0, 64);
    float u1   = __shfl(o0, sl | 1, 64);
    float u2   = __shfl(o0, sl | 2, 64);
    float rhoA = __shfl(o0, sl | 4, 64);
    float gpx  = __shfl(o1, sl | 3, 64);
    float gpy  = __shfl(o2, sl | 3, 64);
    float gpz  = __shfl(o3, sl | 3, 64);
    float c00  = __shfl(o1, sl | 0, 64);
    float c11  = __shfl(o2, sl | 1, 64);
    float c22  = __shfl(o3, sl | 2, 64);
    float rho = 1000.f * (1.f + 0.1f * fast_tanh(rhoA));
    float rr  = __builtin_amdgcn_rcpf(rho);
    float vis = visc[blk*BP + wid*4 + g];
    float lap = a3b[1] + a3b[2] + a3b[3];
    float cv  = u0*o1 + u1*o2 + u2*o3;
    float gp  = (r16 == 0) ? gpx : ((r16 == 1) ? gpy : gpz);
    float R   = a3b[0] + cv + gp*rr - vis*lap + ((r16 == 1) ? 9.81f : 0.f);
    float accM = (r16 < 3) ? R*R : 0.f;
    float accC = 0.f;
    if (r16 == 3){ float Rc = c00 + c11 + c22; accC = Rc*Rc; }
    #pragma unroll
    for (int off = 1; off < 64; off <<= 1){
      accM += __shfl_xor(accM, off, 64);
      accC += __shfl_xor(accC, off, 64);
    }
    if (lane == 0){ red[wid*2] = accM; red[wid*2+1] = accC; }
  }
  __syncthreads();
  if (t == 0){
    float2 pr; pr.x = red[0] + red[2]; pr.y = red[1] + red[3];
    *(float2*)(parts + blk*2) = pr;
  }
}

__global__ void ns_reduce(const float* __restrict__ parts, float* __restrict__ out){
  int t = threadIdx.x;
  float a = 0.f, b = 0.f;
  for (int i = t; i < NBLK; i += 256){ a += parts[2*i]; b += parts[2*i + 1]; }
  #pragma unroll
  for (int off = 32; off; off >>= 1){
    a += __shfl_down(a, off, 64);
    b += __shfl_down(b, off, 64);
  }
  __shared__ float sa[4], sb[4];
  int wid = t >> 6, lane = t & 63;
  if (lane == 0){ sa[wid] = a; sb[wid] = b; }
  __syncthreads();
  if (t == 0){
    float A = sa[0] + sa[1] + sa[2] + sa[3];
    float B = sb[0] + sb[1] + sb[2] + sb[3];
    float mom  = A / (float)NPTS;
    float cont = B / (float)NPTS;
    out[0] = mom + 10.f * cont;
    out[1] = mom;
    out[2] = cont;
  }
}

extern "C" void kernel_launch(void* const* d_in, const int* in_sizes, int n_in,
                              void* d_out, int out_size, void* d_ws, size_t ws_size,
                              hipStream_t stream) {
  const float* pts   = (const float*)d_in[0];
  const float* times = (const float*)d_in[1];
  const float* visc  = (const float*)d_in[2];
  const float* W1    = (const float*)d_in[3];
  const float* b1    = (const float*)d_in[4];
  const float* W2    = (const float*)d_in[5];
  const float* b2    = (const float*)d_in[6];
  const float* W3    = (const float*)d_in[7];
  const float* b3    = (const float*)d_in[8];
  float* out = (float*)d_out;

  unsigned char* w2t = (unsigned char*)d_ws;
  unsigned char* w3t = (unsigned char*)d_ws + W3T_OFF;
  float* parts       = (float*)((char*)d_ws + PART_OFF);

  prep_w2t<<<128, 256, 0, stream>>>(W2, w2t);
  prep_w3t<<<16, 128, 0, stream>>>(W3, w3t);
  ns_main<<<NBLK, 512, 0, stream>>>(pts, times, visc, W1, b1, b2, b3, w2t, w3t, parts);
  ns_reduce<<<1, 256, 0, stream>>>(parts, out);
}

// Round 16
// 109.525 us; speedup vs baseline: 1.5833x; 1.5833x over previous
//
#include <hip/hip_runtime.h>

// NavierStokesLoss: fused jet-propagation (8 channels/point) through
// 4->256->256->5 tanh MLP. R16 = R13 (112.5us, validated) with GEMM2
// switched to mfma_f32_32x32x16_fp8_fp8: half the MFMA issue count
// (256 vs 512 per block), ~20% fewer MFMA cycles, same loads, same
// 32-AGPR acc. 32x32 C layout (col=lane&31, row=(reg&3)+8*(reg>>2)+
// 4*(lane>>5), HW-verified) keeps recombine register-local:
// reg r / r+8 = ch c / c+4 of point (2*(r>>2)+lane>>5).
// Everything else bit-identical to R13 (L1, RC writes, G3 tail, reduce).

#define NPTS 65536
#define BP   8
#define NBLK (NPTS / BP)      // 8192
#define KPADB 264             // byte stride of one W2^T row (256 fp8 + 8 pad)
#define W3T_OFF 135168
#define PART_OFF 143360

typedef float f32x4 __attribute__((ext_vector_type(4)));
typedef float f32x16 __attribute__((ext_vector_type(16)));

static __device__ __forceinline__ unsigned cvtpk_fp8(float lo, float hi){
  unsigned r = 0;
  asm("v_cvt_pk_fp8_f32 %0, %1, %2" : "+v"(r) : "v"(lo), "v"(hi));
  return r;   // bytes [0]=fp8(lo), [1]=fp8(hi)
}
static __device__ __forceinline__ float fast_tanh(float x){
  float e = __builtin_amdgcn_exp2f(x * 2.8853900817779268f);   // exp(2x)
  return 1.f - 2.f * __builtin_amdgcn_rcpf(e + 1.f);
}

// W2 (256x256 f32, [k][j]) -> w2t fp8 [j][KPADB] (transposed, padded rows)
__global__ void prep_w2t(const float* __restrict__ W2, unsigned char* __restrict__ w2t){
  int kp = blockIdx.x, j = threadIdx.x;          // 128 k-pairs
  float lo = W2[(2*kp    )*256 + j];
  float hi = W2[(2*kp + 1)*256 + j];
  *(unsigned short*)(w2t + j*KPADB + 2*kp) = (unsigned short)cvtpk_fp8(lo, hi);
}
// W3 (256x5 f32, [k][n]) -> w3t fp8 [16][256] (transposed, rows 5..15 zero)
__global__ void prep_w3t(const float* __restrict__ W3, unsigned char* __restrict__ w3t){
  int n = blockIdx.x, k2 = threadIdx.x * 2;      // 16 x 128
  float lo = (n < 5) ? W3[k2*5 + n]       : 0.f;
  float hi = (n < 5) ? W3[(k2+1)*5 + n]   : 0.f;
  *(unsigned short*)(w3t + n*256 + k2) = (unsigned short)cvtpk_fp8(lo, hi);
}

// Jet-tile row layout (64 rows x 256 fp8, 256B rows, XOR swizzle (row&15)<<3):
//   row(p,c) = (p&4)*8 + (c&4)*4 + (p&3)*4 + (c&3)
__launch_bounds__(512, 6)
__global__ void ns_main(const float* __restrict__ pts, const float* __restrict__ times,
                        const float* __restrict__ visc,
                        const float* __restrict__ W1, const float* __restrict__ b1,
                        const float* __restrict__ b2, const float* __restrict__ b3,
                        const unsigned char* __restrict__ w2t,
                        const unsigned char* __restrict__ w3t,
                        float* __restrict__ parts){
  __shared__ __align__(16) unsigned char sA[64 * 256];   // 16 KiB
  __shared__ float red[4];

  const int t   = threadIdx.x;
  const int blk = blockIdx.x;

  // ---------------- layer 1: seed the jet, write fp8 A-tile ----------------
  {
    int p  = t >> 6;            // 8 points, one wave each
    int jo = (t & 63) << 2;     // 4 consecutive j per thread
    int n  = blk * BP + p;
    float z0 = pts[n*3+0], z1 = pts[n*3+1], z2 = pts[n*3+2], z3 = times[n];
    float4 wa  = *(const float4*)(W1 + jo);
    float4 wb  = *(const float4*)(W1 + 256 + jo);
    float4 wcv = *(const float4*)(W1 + 512 + jo);
    float4 wd  = *(const float4*)(W1 + 768 + jo);
    float4 bb  = *(const float4*)(b1 + jo);
    float th[4], sg[4], m2[4];
    #pragma unroll
    for (int jj = 0; jj < 4; ++jj){
      float a = (&bb.x)[jj] + z0*(&wa.x)[jj] + z1*(&wb.x)[jj]
                            + z2*(&wcv.x)[jj] + z3*(&wd.x)[jj];
      float h = fast_tanh(a);
      th[jj] = h; sg[jj] = 1.f - h*h; m2[jj] = -2.f*h*sg[jj];
    }
    #pragma unroll
    for (int c = 0; c < 8; ++c){
      float x[4];
      #pragma unroll
      for (int jj = 0; jj < 4; ++jj){
        float w0 = (&wa.x)[jj], w1 = (&wb.x)[jj], w2 = (&wcv.x)[jj];
        float v;
        if      (c == 0) v = th[jj];
        else if (c == 1) v = sg[jj]*w0;
        else if (c == 2) v = sg[jj]*w1;
        else if (c == 3) v = sg[jj]*w2;
        else if (c == 4) v = sg[jj]*(&wd.x)[jj];
        else if (c == 5) v = m2[jj]*w0*w0;
        else if (c == 6) v = m2[jj]*w1*w1;
        else             v = m2[jj]*w2*w2;
        x[jj] = v;
      }
      int row = ((p & 4) << 3) + ((c & 4) << 2) + ((p & 3) << 2) + (c & 3);
      int off = row*256 + (jo ^ ((row & 15) << 3));
      unsigned v32 = cvtpk_fp8(x[0], x[1]) | (cvtpk_fp8(x[2], x[3]) << 16);
      *(unsigned*)(sA + off) = v32;
    }
  }
  __syncthreads();

  const int wid = t >> 6, lane = t & 63;
  const int g = lane >> 4, r16 = lane & 15;
  const int rsw = r16 << 3;          // 16x16-path swizzle (G3)
  const int l31 = lane & 31, h = lane >> 5;
  const int rsw2 = (l31 & 15) << 3;  // 32x32-path swizzle (row&15 of rows l31, 32+l31)

  // ------- GEMM2: A(64x256) @ W2 cols wid*32..+31, 32x32x16 fp8 MFMA -------
  // m-tile mt: jet rows mt*32 + l31 ; B col = wid*32 + l31 ; k-chunk = h*8
  f32x16 acc32[2];
  #pragma unroll
  for (int i = 0; i < 16; ++i){ acc32[0][i] = 0.f; acc32[1][i] = 0.f; }

  {
    const unsigned char* bp2 = w2t + (wid*32 + l31)*KPADB + h*8;
    int abase = l31*256;
    __builtin_amdgcn_s_setprio(1);
    #pragma unroll
    for (int ks = 0; ks < 16; ++ks){
      int k0 = ks * 16;
      int X  = (k0 + (h << 3)) ^ rsw2;
      long a0 = *(const long*)(sA + abase + X);
      long a1 = *(const long*)(sA + abase + 8192 + X);
      long bv = *(const long*)(bp2 + k0);
      acc32[0] = __builtin_amdgcn_mfma_f32_32x32x16_fp8_fp8(a0, bv, acc32[0], 0, 0, 0);
      acc32[1] = __builtin_amdgcn_mfma_f32_32x32x16_fp8_fp8(a1, bv, acc32[1], 0, 0, 0);
    }
    __builtin_amdgcn_s_setprio(0);
  }
  __syncthreads();   // all A-tile reads complete before in-place overwrite

  // ------- recombine (tanh jet through layer-2), register-local, fp8 writes -------
  // acc32[mt] reg r: C row-in-tile = (r&3) + 8*(r>>2) + 4*h ; col j = wid*32+l31.
  // For rr=r>>2 in {0,1}: pt = mt*4 + 2*rr + h, ch = r&3 (lo); reg r+8 = ch+4 (hi).
  {
    float b2j = b2[wid*32 + l31];
    int colj = wid*32 + l31;
    #pragma unroll
    for (int mt = 0; mt < 2; ++mt){
      #pragma unroll
      for (int rr = 0; rr < 2; ++rr){
        int pt = mt*4 + rr*2 + h;
        float gv = fast_tanh(acc32[mt][rr*4 + 0] + b2j);
        float s2 = 1.f - gv*gv;
        float t2 = -2.f * gv * s2;
        int rbase = ((pt & 4) << 3) + ((pt & 3) << 2);
        #pragma unroll
        for (int c3 = 0; c3 < 4; ++c3){
          float lo = acc32[mt][rr*4 + c3];
          float hi = acc32[mt][rr*4 + 8 + c3];
          float r_lo = (c3 == 0) ? gv : s2*lo;
          float r_hi = (c3 == 0) ? s2*hi : fmaf(t2*lo, lo, s2*hi);
          int row = rbase + c3;
          int adr = row*256 + (colj ^ ((row & 15) << 3));
          unsigned u = cvtpk_fp8(r_lo, r_hi);
          *(unsigned char*)(sA + adr)        = (unsigned char)u;
          *(unsigned char*)(sA + adr + 4096) = (unsigned char)(u >> 8);
        }
      }
    }
  }
  __syncthreads();

  // ---- GEMM3 + in-register residual tail: waves 0-1, 4 points each ----
  // (bit-identical to R13; 16x16x32 fp8, tile layout unchanged)
  if (wid < 2){
    const unsigned char* w3p = w3t + r16*256 + g*8;
    int gbase = wid*8192 + r16*256;
    f32x4 a3a = (f32x4){0.f, 0.f, 0.f, 0.f};
    f32x4 a3b = (f32x4){0.f, 0.f, 0.f, 0.f};
    #pragma unroll
    for (int ks = 0; ks < 8; ++ks){
      int k0 = ks * 32;
      int X  = (k0 + (g << 3)) ^ rsw;
      long ava = *(const long*)(sA + gbase + X);
      long avb = *(const long*)(sA + gbase + 4096 + X);
      long bv3 = *(const long*)(w3p + k0);
      a3a = __builtin_amdgcn_mfma_f32_16x16x32_fp8_fp8(ava, bv3, a3a, 0, 0, 0);
      a3b = __builtin_amdgcn_mfma_f32_16x16x32_fp8_fp8(avb, bv3, a3b, 0, 0, 0);
    }
    float b3v = (r16 < 5) ? b3[r16] : 0.f;
    float o0 = a3a[0] + b3v;                   // value channel + bias
    float o1 = a3a[1], o2 = a3a[2], o3 = a3a[3];
    int sl = lane & 48;
    float u0   = __shfl(o0, sl | 0, 64);
    float u1   = __shfl(o0, sl | 1, 64);
    float u2   = __shfl(o0, sl | 2, 64);
    float rhoA = __shfl(o0, sl | 4, 64);
    float gpx  = __shfl(o1, sl | 3, 64);
    float gpy  = __shfl(o2, sl | 3, 64);
    float gpz  = __shfl(o3, sl | 3, 64);
    float c00  = __shfl(o1, sl | 0, 64);
    float c11  = __shfl(o2, sl | 1, 64);
    float c22  = __shfl(o3, sl | 2, 64);
    float rho = 1000.f * (1.f + 0.1f * fast_tanh(rhoA));
    float rr  = __builtin_amdgcn_rcpf(rho);
    float vis = visc[blk*BP + wid*4 + g];
    float lap = a3b[1] + a3b[2] + a3b[3];
    float cv  = u0*o1 + u1*o2 + u2*o3;
    float gp  = (r16 == 0) ? gpx : ((r16 == 1) ? gpy : gpz);
    float R   = a3b[0] + cv + gp*rr - vis*lap + ((r16 == 1) ? 9.81f : 0.f);
    float accM = (r16 < 3) ? R*R : 0.f;
    float accC = 0.f;
    if (r16 == 3){ float Rc = c00 + c11 + c22; accC = Rc*Rc; }
    #pragma unroll
    for (int off = 1; off < 64; off <<= 1){
      accM += __shfl_xor(accM, off, 64);
      accC += __shfl_xor(accC, off, 64);
    }
    if (lane == 0){ red[wid*2] = accM; red[wid*2+1] = accC; }
  }
  __syncthreads();
  if (t == 0){
    float2 pr; pr.x = red[0] + red[2]; pr.y = red[1] + red[3];
    *(float2*)(parts + blk*2) = pr;
  }
}

__global__ void ns_reduce(const float* __restrict__ parts, float* __restrict__ out){
  int t = threadIdx.x;
  float a = 0.f, b = 0.f;
  for (int i = t; i < NBLK; i += 256){ a += parts[2*i]; b += parts[2*i + 1]; }
  #pragma unroll
  for (int off = 32; off; off >>= 1){
    a += __shfl_down(a, off, 64);
    b += __shfl_down(b, off, 64);
  }
  __shared__ float sa[4], sb[4];
  int wid = t >> 6, lane = t & 63;
  if (lane == 0){ sa[wid] = a; sb[wid] = b; }
  __syncthreads();
  if (t == 0){
    float A = sa[0] + sa[1] + sa[2] + sa[3];
    float B = sb[0] + sb[1] + sb[2] + sb[3];
    float mom  = A / (float)NPTS;
    float cont = B / (float)NPTS;
    out[0] = mom + 10.f * cont;
    out[1] = mom;
    out[2] = cont;
  }
}

extern "C" void kernel_launch(void* const* d_in, const int* in_sizes, int n_in,
                              void* d_out, int out_size, void* d_ws, size_t ws_size,
                              hipStream_t stream) {
  const float* pts   = (const float*)d_in[0];
  const float* times = (const float*)d_in[1];
  const float* visc  = (const float*)d_in[2];
  const float* W1    = (const float*)d_in[3];
  const float* b1    = (const float*)d_in[4];
  const float* W2    = (const float*)d_in[5];
  const float* b2    = (const float*)d_in[6];
  const float* W3    = (const float*)d_in[7];
  const float* b3    = (const float*)d_in[8];
  float* out = (float*)d_out;

  unsigned char* w2t = (unsigned char*)d_ws;
  unsigned char* w3t = (unsigned char*)d_ws + W3T_OFF;
  float* parts       = (float*)((char*)d_ws + PART_OFF);

  prep_w2t<<<128, 256, 0, stream>>>(W2, w2t);
  prep_w3t<<<16, 128, 0, stream>>>(W3, w3t);
  ns_main<<<NBLK, 512, 0, stream>>>(pts, times, visc, W1, b1, b2, b3, w2t, w3t, parts);
  ns_reduce<<<1, 256, 0, stream>>>(parts, out);
}